// Round 8
// baseline (502.386 us; speedup 1.0000x reference)
//
#include <hip/hip_runtime.h>
#include <hip/hip_bf16.h>

// ---------------------------------------------------------------------------
// AMMN_Net: dual 2-layer GCN + gated fusion head.
// R8: feature-sliced, XCD-pinned aggregation. Features stored slice-major
// featS[8][n][16bf16] (32 B). Agg blocks: slice = blockIdx.x & 7 -> with
// round-robin workgroup->XCD dispatch each XCD gathers from a 3.2 MB slab
// that FITS its 4 MB L2 (prev: 25.6 MB thrash, 201 MB fabric traffic/pass).
// Lane map: 2 lanes/edge (16B), 2 slots/node, 16 nodes/wave (degree-sorted),
// shfl_xor(2) reduce. GEMM1 epilogue + A-fragments re-indexed slice-major.
// Rest as R6/R7: bucketed ELL build, MFMA GEMMs (swapped operands), fused BN,
// gathered head GEMM + fused epilogue, degree counting sort.
// ---------------------------------------------------------------------------

#define ELL_CAP 64
#define BCAP 8192
#define ACHUNK 5120

typedef __attribute__((ext_vector_type(8))) short short8v;   // 8 bf16
typedef __attribute__((ext_vector_type(4))) float f32x4;

static __device__ __forceinline__ float wred64(float v) {
#pragma unroll
  for (int m = 32; m; m >>= 1) v += __shfl_xor(v, m, 64);
  return v;
}

static __device__ __forceinline__ unsigned short f2bf(float f) {
  unsigned u = __float_as_uint(f);
  unsigned r = (u + 0x7fffu + ((u >> 16) & 1u)) >> 16;  // RNE
  return (unsigned short)r;
}
static __device__ __forceinline__ unsigned packbf(float a, float b) {
  return (unsigned)f2bf(a) | ((unsigned)f2bf(b) << 16);
}
static __device__ __forceinline__ float bflo(unsigned u) {
  return __uint_as_float(u << 16);
}
static __device__ __forceinline__ float bfhi(unsigned u) {
  return __uint_as_float(u & 0xffff0000u);
}

// prep: x -> slice-major bf16 featS[8][n][16]; pack Wb1/Wb2(blockdiag)/WbH;
// biases; init gbump + stats + ghist.
__global__ void k_prep(const float* __restrict__ x, unsigned* __restrict__ xS,
                       int* __restrict__ gbump, float* __restrict__ stats,
                       int* __restrict__ ghist,
                       const float* __restrict__ W1g, const float* __restrict__ b1g,
                       const float* __restrict__ W1s, const float* __restrict__ b1s,
                       const float* __restrict__ W2g, const float* __restrict__ b2g,
                       const float* __restrict__ W2s, const float* __restrict__ b2s,
                       const float* __restrict__ Wf1,
                       short* __restrict__ Wb1, short* __restrict__ Wb2,
                       short* __restrict__ WbH, float* __restrict__ bc1,
                       float* __restrict__ bc2, int n, int NB) {
  int idx = blockIdx.x * 256 + threadIdx.x;
  if (idx < n * 8) {
    int s = idx / n;            // slice
    int node = idx - s * n;
    const float4* xp = (const float4*)(x + (size_t)node * 128 + s * 16);
    float4 a = xp[0], b = xp[1], c = xp[2], d = xp[3];
    uint4 o0, o1;
    o0.x = packbf(a.x, a.y); o0.y = packbf(a.z, a.w);
    o0.z = packbf(b.x, b.y); o0.w = packbf(b.z, b.w);
    o1.x = packbf(c.x, c.y); o1.y = packbf(c.z, c.w);
    o1.z = packbf(d.x, d.y); o1.w = packbf(d.z, d.w);
    uint4* op = (uint4*)xS + (size_t)idx * 2;  // (s*n+node)*2
    op[0] = o0;
    op[1] = o1;
  }
  if (idx < 16384) {
    int k = idx >> 7, c = idx & 127;
    int pi = (k >> 3) * 1024 + c * 8 + (k & 7);  // [k/8][c][k&7]
    float w1 = (c < 64) ? W1g[k * 64 + c] : W1s[k * 64 + (c - 64)];
    Wb1[pi] = (short)f2bf(w1);
    float w2 = 0.f;
    if (k < 64 && c < 64) w2 = W2g[k * 64 + c];
    else if (k >= 64 && c >= 64) w2 = W2s[(k - 64) * 64 + (c - 64)];
    Wb2[pi] = (short)f2bf(w2);
    WbH[pi] = (short)f2bf(Wf1[k * 128 + c]);
  }
  if (idx < 128) {
    bc1[idx] = (idx < 64) ? b1g[idx] : b1s[idx - 64];
    bc2[idx] = (idx < 64) ? b2g[idx] : b2s[idx - 64];
  }
  if (idx < NB) gbump[idx] = idx * BCAP;
  if (idx < 2048) stats[idx] = 0.f;
  if (idx < 65) ghist[idx] = 0;
}

// Pass A: bucket edges by dst>>8 (one global atomic per block-bucket)
__global__ __launch_bounds__(256) void k_bucketA(
    const int* __restrict__ src, const int* __restrict__ dst,
    int* __restrict__ gbump, unsigned* __restrict__ ebuf, int E, int NB) {
  __shared__ int hist[512];
  __shared__ int gbase[512];
  int t = threadIdx.x;
  int e0 = blockIdx.x * ACHUNK;
  int m = min(ACHUNK, E - e0);
  for (int b = t; b < NB; b += 256) hist[b] = 0;
  __syncthreads();
  for (int i = t; i < m; i += 256) atomicAdd(&hist[dst[e0 + i] >> 8], 1);
  __syncthreads();
  for (int b = t; b < NB; b += 256) {
    gbase[b] = hist[b] ? atomicAdd(&gbump[b], hist[b]) : 0;
    hist[b] = 0;
  }
  __syncthreads();
  for (int i = t; i < m; i += 256) {
    int d = dst[e0 + i];
    int s = src[e0 + i];
    int b = d >> 8;
    int off = gbase[b] + atomicAdd(&hist[b], 1);
    if (off < (b + 1) * BCAP)
      ebuf[off] = ((unsigned)s << 8) | (unsigned)(d & 255);
  }
}

// Pass B: block-per-bucket; LDS bump -> ELL col + cnt + dinv
__global__ __launch_bounds__(256) void k_csrB(
    const unsigned* __restrict__ ebuf, const int* __restrict__ gbump,
    int* __restrict__ cnt, float* __restrict__ dinv, int* __restrict__ col,
    int n) {
  __shared__ int lbump[256];
  int b = blockIdx.x;
  lbump[threadIdx.x] = 0;
  __syncthreads();
  int base = b * BCAP;
  int m = min(gbump[b] - base, BCAP);
  for (int i = threadIdx.x; i < m; i += 256) {
    unsigned p = ebuf[base + i];
    int dloc = p & 255;
    int slot = atomicAdd(&lbump[dloc], 1);
    if (slot < ELL_CAP)
      col[(b * 256 + dloc) * ELL_CAP + slot] = (int)(p >> 8);
  }
  __syncthreads();
  int node = b * 256 + threadIdx.x;
  if (node < n) {
    int c = lbump[threadIdx.x];
    cnt[node] = c;
    dinv[node] = rsqrtf((float)(c + 1));
  }
}

// ---- degree counting sort: hist -> scan(descending) -> scatter ----
__global__ void k_hist(const int* __restrict__ cnt, int* __restrict__ ghist, int n) {
  __shared__ int h[65];
  if (threadIdx.x < 65) h[threadIdx.x] = 0;
  __syncthreads();
  int i = blockIdx.x * 256 + threadIdx.x;
  if (i < n) atomicAdd(&h[min(cnt[i], 64)], 1);
  __syncthreads();
  if (threadIdx.x < 65 && h[threadIdx.x]) atomicAdd(&ghist[threadIdx.x], h[threadIdx.x]);
}

__global__ void k_scan65(const int* __restrict__ ghist, int* __restrict__ gbase) {
  if (threadIdx.x == 0) {
    int a = 0;
    for (int b = 64; b >= 0; --b) {
      gbase[b] = a;
      a += ghist[b];
    }
  }
}

__global__ void k_scatter(const int* __restrict__ cnt, int* __restrict__ gbase,
                          int* __restrict__ perm, int n) {
  __shared__ int h[65];
  __shared__ int base[65];
  if (threadIdx.x < 65) h[threadIdx.x] = 0;
  __syncthreads();
  int i = blockIdx.x * 256 + threadIdx.x;
  int b = -1, r = 0;
  if (i < n) {
    b = min(cnt[i], 64);
    r = atomicAdd(&h[b], 1);
  }
  __syncthreads();
  if (threadIdx.x < 65 && h[threadIdx.x])
    base[threadIdx.x] = atomicAdd(&gbase[threadIdx.x], h[threadIdx.x]);
  __syncthreads();
  if (b >= 0) perm[base[b] + r] = i;
}

// Sliced, XCD-pinned aggregation. featS/outS: [8][n][16 bf16] (32 B rows).
// slice = blockIdx.x & 7; 2 lanes/edge, 2 slots/node, 16 nodes/wave.
template <bool BN>
__global__ __launch_bounds__(256) void k_agg(
    const unsigned* __restrict__ featS, unsigned* __restrict__ outS,
    const int* __restrict__ perm, const int* __restrict__ cnt,
    const float* __restrict__ dinv, const int* __restrict__ col,
    const float* __restrict__ stats, const float* __restrict__ g1g,
    const float* __restrict__ be1g, const float* __restrict__ g1s,
    const float* __restrict__ be1s, float inv_n, int n) {
  int s = blockIdx.x & 7;
  int ng = blockIdx.x >> 3;
  __shared__ float sc_sh[16], sf_sh[16];
  if (BN) {
    int t = threadIdx.x;
    if (t < 16) {
      int c = s * 16 + t;
      float su = 0.f, q = 0.f;
#pragma unroll
      for (int k = 0; k < 8; k++) {
        su += stats[k * 256 + c];
        q += stats[k * 256 + 128 + c];
      }
      float mu = su * inv_n;
      float var = q * inv_n - mu * mu;
      float gam = (c < 64) ? g1g[c] : g1s[c - 64];
      float bet = (c < 64) ? be1g[c] : be1s[c - 64];
      float scv = gam * rsqrtf(var + 1e-5f);
      sc_sh[t] = scv;
      sf_sh[t] = bet - mu * scv;
    }
    __syncthreads();
  }
  int lane = threadIdx.x & 63;
  int wv = threadIdx.x >> 6;
  int half = lane & 1;         // which 16B of the 32B slice row
  int slot = (lane >> 1) & 1;  // 2 edge slots per node
  int g = ng * 64 + wv * 16 + (lane >> 2);
  if (g >= n) return;
  int node = perm[g];
  int cn = min(cnt[node], ELL_CAP);
  float di = dinv[node];
  float sc[8], sf[8];
  if (BN) {
#pragma unroll
    for (int j = 0; j < 8; j++) {
      sc[j] = sc_sh[half * 8 + j];
      sf[j] = sf_sh[half * 8 + j];
    }
  }
  const uint4* F = (const uint4*)featS;
  int sb = s * n;  // slice slab base (32B units)
  float acc[8];
#pragma unroll
  for (int j = 0; j < 8; j++) acc[j] = 0.f;
  const int* cl = col + node * ELL_CAP;
  for (int i = slot; i < cn; i += 2) {
    int src = cl[i];
    float w = dinv[src];
    uint4 v = F[(size_t)(sb + src) * 2 + half];
    float f[8] = {bflo(v.x), bfhi(v.x), bflo(v.y), bfhi(v.y),
                  bflo(v.z), bfhi(v.z), bflo(v.w), bfhi(v.w)};
#pragma unroll
    for (int j = 0; j < 8; j++) {
      if (BN) f[j] = fmaxf(f[j] * sc[j] + sf[j], 0.f);
      acc[j] += f[j] * w;
    }
  }
  if (slot == 0) {  // self term
    uint4 v = F[(size_t)(sb + node) * 2 + half];
    float f[8] = {bflo(v.x), bfhi(v.x), bflo(v.y), bfhi(v.y),
                  bflo(v.z), bfhi(v.z), bflo(v.w), bfhi(v.w)};
#pragma unroll
    for (int j = 0; j < 8; j++) {
      if (BN) f[j] = fmaxf(f[j] * sc[j] + sf[j], 0.f);
      acc[j] += f[j] * di;
    }
  }
#pragma unroll
  for (int j = 0; j < 8; j++) acc[j] += __shfl_xor(acc[j], 2, 64);
  if (slot == 0) {
    uint4 o;
    o.x = packbf(acc[0] * di, acc[1] * di);
    o.y = packbf(acc[2] * di, acc[3] * di);
    o.z = packbf(acc[4] * di, acc[5] * di);
    o.w = packbf(acc[6] * di, acc[7] * di);
    ((uint4*)outS)[(size_t)(sb + node) * 2 + half] = o;
  }
}

// MFMA GEMM (swapped operands): lane owns row rowbase+(lane&15),
// cols nt*16+(lane>>4)*4+r. A (bf16) read from slice-major [8][M][16];
// CBF16 -> write slice-major bf16; else fp32 row-major (+blockIdx.y slab).
template <bool CBF16, bool STATS, bool TANH, bool GATHER>
__global__ __launch_bounds__(256) void k_mgemm(
    const unsigned* __restrict__ Abf, const float* __restrict__ nodes,
    const int* __restrict__ users, const int* __restrict__ items,
    const short* __restrict__ Wb, const float* __restrict__ bias,
    void* __restrict__ Cvp, int M, float* __restrict__ stats) {
  __shared__ short Wl[16384];   // 32 KB
  __shared__ float shs[128], shq[128];
  {
    const uint4* s4 = (const uint4*)Wb;
    uint4* d4 = (uint4*)Wl;
    for (int i = threadIdx.x; i < 2048; i += 256) d4[i] = s4[i];
  }
  if (STATS && threadIdx.x < 128) { shs[threadIdx.x] = 0.f; shq[threadIdx.x] = 0.f; }
  __syncthreads();
  int lane = threadIdx.x & 63;
  int wv = threadIdx.x >> 6;
  int l15 = lane & 15;
  int l4 = lane >> 4;
  int row = blockIdx.x * 64 + wv * 16 + l15;
  int rc = min(row, M - 1);
  bool valid = row < M;

  short8v afr[4];
  if (GATHER) {
    int fo = blockIdx.y * 64;
    const float* pu = nodes + (size_t)users[rc] * 128 + fo;
    const float* pi = nodes + (size_t)items[rc] * 128 + fo;
#pragma unroll
    for (int ks = 0; ks < 4; ks++) {
      int k = ks * 32 + l4 * 8;
      const float* p = (ks < 2) ? (pu + k) : (pi + (k - 64));
      float4 x0 = *(const float4*)p;
      float4 x1 = *(const float4*)(p + 4);
      union { short s[8]; short8v v; } u;
      u.s[0] = (short)f2bf(x0.x); u.s[1] = (short)f2bf(x0.y);
      u.s[2] = (short)f2bf(x0.z); u.s[3] = (short)f2bf(x0.w);
      u.s[4] = (short)f2bf(x1.x); u.s[5] = (short)f2bf(x1.y);
      u.s[6] = (short)f2bf(x1.z); u.s[7] = (short)f2bf(x1.w);
      afr[ks] = u.v;
    }
  } else {
    // slice-major: feats ks*32 + l4*8 -> slice 2ks+(l4>>1), 16B half (l4&1)
#pragma unroll
    for (int ks = 0; ks < 4; ks++) {
      int sl = 2 * ks + (l4 >> 1);
      const uint4* p = (const uint4*)Abf + (size_t)(sl * M + rc) * 2 + (l4 & 1);
      afr[ks] = *(const short8v*)p;
    }
  }

  f32x4 acc[8];
#pragma unroll
  for (int nt = 0; nt < 8; nt++) acc[nt] = (f32x4){0.f, 0.f, 0.f, 0.f};
#pragma unroll
  for (int nt = 0; nt < 8; nt++) {
#pragma unroll
    for (int ks = 0; ks < 4; ks++) {
      int kb = ks * 4 + l4;
      short8v w = *(const short8v*)&Wl[kb * 1024 + (nt * 16 + l15) * 8];
      acc[nt] = __builtin_amdgcn_mfma_f32_16x16x32_bf16(w, afr[ks], acc[nt], 0, 0, 0);
    }
  }

#pragma unroll
  for (int nt = 0; nt < 8; nt++) {
    int c0 = nt * 16 + l4 * 4;
    float o[4];
#pragma unroll
    for (int r = 0; r < 4; r++) o[r] = acc[nt][r];
    if (bias) {
      float4 bv = *(const float4*)(bias + c0);
      o[0] += bv.x; o[1] += bv.y; o[2] += bv.z; o[3] += bv.w;
    }
    if (TANH) {
#pragma unroll
      for (int r = 0; r < 4; r++) o[r] = tanhf(o[r]);
    }
    if (STATS) {
      float su[4], q[4];
#pragma unroll
      for (int r = 0; r < 4; r++) {
        su[r] = valid ? o[r] : 0.f;
        q[r] = su[r] * su[r];
      }
#pragma unroll
      for (int m = 1; m < 16; m <<= 1) {
#pragma unroll
        for (int r = 0; r < 4; r++) {
          su[r] += __shfl_xor(su[r], m, 64);
          q[r] += __shfl_xor(q[r], m, 64);
        }
      }
      if (l15 == 0) {
#pragma unroll
        for (int r = 0; r < 4; r++) {
          atomicAdd(&shs[c0 + r], su[r]);
          atomicAdd(&shq[c0 + r], q[r]);
        }
      }
    }
    if (valid) {
      if (CBF16) {
        // slice-major write: slice nt, in-slice byte offset l4*8
        unsigned* Cb = (unsigned*)Cvp;
        uint2 p;
        p.x = packbf(o[0], o[1]);
        p.y = packbf(o[2], o[3]);
        *(uint2*)&Cb[(size_t)(nt * M + row) * 8 + l4 * 2] = p;
      } else {
        float* Cf = (float*)Cvp + (size_t)blockIdx.y * M * 128;
        *(float4*)&Cf[(size_t)row * 128 + c0] = make_float4(o[0], o[1], o[2], o[3]);
      }
    }
  }
  if (STATS) {
    __syncthreads();
    if (threadIdx.x < 128) {
      float* st = stats + (blockIdx.x & 7) * 256;
      atomicAdd(&st[threadIdx.x], shs[threadIdx.x]);
      atomicAdd(&st[128 + threadIdx.x], shq[threadIdx.x]);
    }
  }
}

__global__ void k_head(const float* __restrict__ G1, const float* __restrict__ G2,
                       const float* __restrict__ nodes, const int* __restrict__ users,
                       const int* __restrict__ items, const float* __restrict__ Wsig,
                       const float* __restrict__ Wtc, const float* __restrict__ btc,
                       const float* __restrict__ Wp, const float* __restrict__ bp,
                       float* __restrict__ out, int B) {
  int l = threadIdx.x & 63;
  int wave = (blockIdx.x * 256 + threadIdx.x) >> 6;
  int nw = (gridDim.x * 256) >> 6;
  for (int b = wave; b < B; b += nw) {
    const float* g1 = G1 + (size_t)b * 128;
    const float* g2 = G2 + (size_t)b * 128;
    int u = users[b], it = items[b];
    float h1a = g1[l], h1b = g1[64 + l];
    float h2a = g2[l], h2b = g2[64 + l];
    float ga = nodes[(size_t)u * 128 + l];
    float gb = nodes[(size_t)it * 128 + l];
    float zp = h1a * Wsig[l] + h1b * Wsig[64 + l] + h2a * Wsig[128 + l] + h2b * Wsig[192 + l];
    float z = wred64(zp);
    z = 1.f / (1.f + expf(-z));
    float fa = z * h1a + (1.f - z) * h2a;
    float fb = z * h1b + (1.f - z) * h2b;
    float p0 = wred64(fa * Wp[l * 2] + fb * Wp[(64 + l) * 2]);
    float p1 = wred64(fa * Wp[l * 2 + 1] + fb * Wp[(64 + l) * 2 + 1]);
    float t0 = wred64(ga * Wtc[l * 4] + gb * Wtc[(64 + l) * 4]);
    float t1 = wred64(ga * Wtc[l * 4 + 1] + gb * Wtc[(64 + l) * 4 + 1]);
    float t2 = wred64(ga * Wtc[l * 4 + 2] + gb * Wtc[(64 + l) * 4 + 2]);
    float t3 = wred64(ga * Wtc[l * 4 + 3] + gb * Wtc[(64 + l) * 4 + 3]);
    if (l == 0) {
      out[b * 2] = p0 + bp[0];
      out[b * 2 + 1] = p1 + bp[1];
      float* go = out + 2 * B;
      go[b * 4] = t0 + btc[0];
      go[b * 4 + 1] = t1 + btc[1];
      go[b * 4 + 2] = t2 + btc[2];
      go[b * 4 + 3] = t3 + btc[3];
    }
  }
}

extern "C" void kernel_launch(void* const* d_in, const int* in_sizes, int n_in,
                              void* d_out, int out_size, void* d_ws, size_t ws_size,
                              hipStream_t stream) {
  const float* x = (const float*)d_in[0];
  const int* ei = (const int*)d_in[1];
  const int* users = (const int*)d_in[2];
  const int* items = (const int*)d_in[3];
  const float* W1g = (const float*)d_in[4];
  const float* b1g = (const float*)d_in[5];
  const float* g1g = (const float*)d_in[6];
  const float* be1g = (const float*)d_in[7];
  const float* W2g = (const float*)d_in[8];
  const float* b2g = (const float*)d_in[9];
  const float* W1s = (const float*)d_in[10];
  const float* b1s = (const float*)d_in[11];
  const float* g1s = (const float*)d_in[12];
  const float* be1s = (const float*)d_in[13];
  const float* W2s = (const float*)d_in[14];
  const float* b2s = (const float*)d_in[15];
  const float* Wf1 = (const float*)d_in[16];
  const float* Wsig = (const float*)d_in[17];
  const float* Wtc = (const float*)d_in[18];
  const float* btc = (const float*)d_in[19];
  const float* Wp = (const float*)d_in[20];
  const float* bp = (const float*)d_in[21];

  int n = in_sizes[0] / 128;   // 100000
  int E = in_sizes[1] / 2;     // 1600000
  int B = in_sizes[2];         // 16384
  int NB = (n + 255) >> 8;     // 391
  const int* srcp = ei;
  const int* dstp = ei + E;
  float* out = (float*)d_out;

  char* w = (char*)d_ws;
  auto alloc = [&](size_t bytes) -> char* {
    char* p = w;
    w += (bytes + 255) & ~(size_t)255;
    return p;
  };
  unsigned* xab = (unsigned*)alloc((size_t)n * 64 * 4);     // agg out, slice-major
  float* big1 = (float*)alloc((size_t)n * 128 * 4);         // hbS bf16 -> nodes fp32
  unsigned* bff = (unsigned*)alloc((size_t)n * 128 * 2);    // xS; later G1/G2
  int* col = (int*)alloc((size_t)n * ELL_CAP * 4);          // ELL
  unsigned* ebuf = (unsigned*)alloc((size_t)NB * BCAP * 4); // bucketed edges
  int* cnt = (int*)alloc((size_t)n * 4);
  float* dinv = (float*)alloc((size_t)n * 4);
  int* perm = (int*)alloc((size_t)n * 4);
  int* gbump = (int*)alloc(512 * 4);
  int* ghist = (int*)alloc(128 * 4);
  int* gbase = (int*)alloc(128 * 4);
  short* Wb1 = (short*)alloc(16384 * 2);
  short* Wb2 = (short*)alloc(16384 * 2);
  short* WbH = (short*)alloc(16384 * 2);
  float* bc1 = (float*)alloc(512);
  float* bc2 = (float*)alloc(512);
  float* stats = (float*)alloc(2048 * 4);

  int nb = (n + 255) / 256;  // 391

  k_prep<<<(n * 16 + 255) / 256, 256, 0, stream>>>(
      x, bff, gbump, stats, ghist, W1g, b1g, W1s, b1s, W2g, b2g, W2s, b2s, Wf1,
      Wb1, Wb2, WbH, bc1, bc2, n, NB);
  k_bucketA<<<(E + ACHUNK - 1) / ACHUNK, 256, 0, stream>>>(srcp, dstp, gbump, ebuf, E, NB);
  k_csrB<<<NB, 256, 0, stream>>>(ebuf, gbump, cnt, dinv, col, n);

  // degree counting sort -> perm (descending degree)
  k_hist<<<nb, 256, 0, stream>>>(cnt, ghist, n);
  k_scan65<<<1, 64, 0, stream>>>(ghist, gbase);
  k_scatter<<<nb, 256, 0, stream>>>(cnt, gbase, perm, n);

  unsigned* hb = (unsigned*)big1;

  int aggGrid = ((n + 63) / 64) * 8;  // slice = blockIdx & 7 (XCD-pinned)

  // layer 1: xaS = S@xS; h = xa @ [W1g|W1s] + bc1 (slice-major bf16, BN stats)
  k_agg<false><<<aggGrid, 256, 0, stream>>>(bff, xab, perm, cnt, dinv, col,
                                            nullptr, nullptr, nullptr, nullptr,
                                            nullptr, 0.f, n);
  k_mgemm<true, true, false, false><<<(n + 63) / 64, 256, 0, stream>>>(
      xab, nullptr, nullptr, nullptr, Wb1, bc1, hb, n, stats);

  // layer 2: haS = S@relu(bn(hS)); nodes = ha @ blockdiag(W2g,W2s) + bc2 (fp32)
  k_agg<true><<<aggGrid, 256, 0, stream>>>(hb, xab, perm, cnt, dinv, col,
                                           stats, g1g, be1g, g1s, be1s,
                                           1.f / (float)n, n);
  k_mgemm<false, false, false, false><<<(n + 63) / 64, 256, 0, stream>>>(
      xab, nullptr, nullptr, nullptr, Wb2, bc2, big1, n, nullptr);

  // head: gathered tanh-GEMMs (y=0 gen->G1, y=1 spec->G2) + fused epilogue
  float* G1 = (float*)bff;
  dim3 gh((B + 63) / 64, 2);
  k_mgemm<false, false, true, true><<<gh, 256, 0, stream>>>(
      nullptr, big1, users, items, WbH, nullptr, G1, B, nullptr);
  float* G2 = G1 + (size_t)B * 128;
  k_head<<<2048, 256, 0, stream>>>(G1, G2, big1, users, items, Wsig, Wtc, btc,
                                   Wp, bp, out, B);
}

// Round 9
// 275.811 us; speedup vs baseline: 1.8215x; 1.8215x over previous
//
#include <hip/hip_runtime.h>
#include <hip/hip_bf16.h>

// ---------------------------------------------------------------------------
// AMMN_Net: dual 2-layer GCN + gated fusion head.
// R9 = R6 (best verified structure) + targeted deltas:
//  - k_agg: R6 lane map (16 lanes/node, 256B rows) + dinv table + 8-deep
//    unroll for MLP. NO degree sort (R7 net-negative), NO slicing (R8 failed:
//    8x metadata re-read).
//  - GEMM2 writes nodes as bf16; head GEMM gathers bf16 rows directly;
//    k_head reads bf16 nodes.
// Pipeline: bucketed ELL build -> agg1 -> MFMA GEMM1 (BN stats fused) ->
// agg2 (BN+ReLU fused) -> MFMA GEMM2 (block-diag) -> gathered head GEMM ->
// fused head epilogue. 9 kernel launches.
// ---------------------------------------------------------------------------

#define ELL_CAP 64
#define BCAP 8192
#define ACHUNK 5120

typedef __attribute__((ext_vector_type(8))) short short8v;   // 8 bf16
typedef __attribute__((ext_vector_type(4))) float f32x4;

static __device__ __forceinline__ float wred64(float v) {
#pragma unroll
  for (int m = 32; m; m >>= 1) v += __shfl_xor(v, m, 64);
  return v;
}

static __device__ __forceinline__ unsigned short f2bf(float f) {
  unsigned u = __float_as_uint(f);
  unsigned r = (u + 0x7fffu + ((u >> 16) & 1u)) >> 16;  // RNE
  return (unsigned short)r;
}
static __device__ __forceinline__ unsigned packbf(float a, float b) {
  return (unsigned)f2bf(a) | ((unsigned)f2bf(b) << 16);
}
static __device__ __forceinline__ float bflo(unsigned u) {
  return __uint_as_float(u << 16);
}
static __device__ __forceinline__ float bfhi(unsigned u) {
  return __uint_as_float(u & 0xffff0000u);
}

// prep: x->bf16 row-major; pack Wb1/Wb2(block-diag)/WbH bf16 [k/8][128][8];
// biases; init gbump + stats.
__global__ void k_prep(const float* __restrict__ x, unsigned* __restrict__ bff,
                       int* __restrict__ gbump, float* __restrict__ stats,
                       const float* __restrict__ W1g, const float* __restrict__ b1g,
                       const float* __restrict__ W1s, const float* __restrict__ b1s,
                       const float* __restrict__ W2g, const float* __restrict__ b2g,
                       const float* __restrict__ W2s, const float* __restrict__ b2s,
                       const float* __restrict__ Wf1,
                       short* __restrict__ Wb1, short* __restrict__ Wb2,
                       short* __restrict__ WbH, float* __restrict__ bc1,
                       float* __restrict__ bc2, int n, int NB) {
  int idx = blockIdx.x * 256 + threadIdx.x;
  int n16 = n * 16;
  if (idx < n16) {
    const float4* f4 = (const float4*)x;
    float4 a = f4[idx * 2], b = f4[idx * 2 + 1];
    uint4 o;
    o.x = packbf(a.x, a.y);
    o.y = packbf(a.z, a.w);
    o.z = packbf(b.x, b.y);
    o.w = packbf(b.z, b.w);
    ((uint4*)bff)[idx] = o;
  }
  if (idx < 16384) {
    int k = idx >> 7, c = idx & 127;
    int pi = (k >> 3) * 1024 + c * 8 + (k & 7);  // [k/8][c][k&7]
    float w1 = (c < 64) ? W1g[k * 64 + c] : W1s[k * 64 + (c - 64)];
    Wb1[pi] = (short)f2bf(w1);
    float w2 = 0.f;
    if (k < 64 && c < 64) w2 = W2g[k * 64 + c];
    else if (k >= 64 && c >= 64) w2 = W2s[(k - 64) * 64 + (c - 64)];
    Wb2[pi] = (short)f2bf(w2);
    WbH[pi] = (short)f2bf(Wf1[k * 128 + c]);
  }
  if (idx < 128) {
    bc1[idx] = (idx < 64) ? b1g[idx] : b1s[idx - 64];
    bc2[idx] = (idx < 64) ? b2g[idx] : b2s[idx - 64];
  }
  if (idx < NB) gbump[idx] = idx * BCAP;
  if (idx < 2048) stats[idx] = 0.f;
}

// Pass A: bucket edges by dst>>8 (one global atomic per block-bucket)
__global__ __launch_bounds__(256) void k_bucketA(
    const int* __restrict__ src, const int* __restrict__ dst,
    int* __restrict__ gbump, unsigned* __restrict__ ebuf, int E, int NB) {
  __shared__ int hist[512];
  __shared__ int gbase[512];
  int t = threadIdx.x;
  int e0 = blockIdx.x * ACHUNK;
  int m = min(ACHUNK, E - e0);
  for (int b = t; b < NB; b += 256) hist[b] = 0;
  __syncthreads();
  for (int i = t; i < m; i += 256) atomicAdd(&hist[dst[e0 + i] >> 8], 1);
  __syncthreads();
  for (int b = t; b < NB; b += 256) {
    gbase[b] = hist[b] ? atomicAdd(&gbump[b], hist[b]) : 0;
    hist[b] = 0;
  }
  __syncthreads();
  for (int i = t; i < m; i += 256) {
    int d = dst[e0 + i];
    int s = src[e0 + i];
    int b = d >> 8;
    int off = gbase[b] + atomicAdd(&hist[b], 1);
    if (off < (b + 1) * BCAP)
      ebuf[off] = ((unsigned)s << 8) | (unsigned)(d & 255);
  }
}

// Pass B: block-per-bucket; LDS bump -> ELL col + capped cnt + dinv
__global__ __launch_bounds__(256) void k_csrB(
    const unsigned* __restrict__ ebuf, const int* __restrict__ gbump,
    int* __restrict__ cnt, float* __restrict__ dinv, int* __restrict__ col,
    int n) {
  __shared__ int lbump[256];
  int b = blockIdx.x;
  lbump[threadIdx.x] = 0;
  __syncthreads();
  int base = b * BCAP;
  int m = min(gbump[b] - base, BCAP);
  for (int i = threadIdx.x; i < m; i += 256) {
    unsigned p = ebuf[base + i];
    int dloc = p & 255;
    int slot = atomicAdd(&lbump[dloc], 1);
    if (slot < ELL_CAP)
      col[(b * 256 + dloc) * ELL_CAP + slot] = (int)(p >> 8);
  }
  __syncthreads();
  int node = b * 256 + threadIdx.x;
  if (node < n) {
    int c = lbump[threadIdx.x];
    cnt[node] = min(c, ELL_CAP);
    dinv[node] = rsqrtf((float)(c + 1));  // true degree for norm
  }
}

// aggregation: 16 lanes/node (uint4 = 16B, full 256B bf16 row), 8-deep unroll,
// dinv table. Optional fused BN+ReLU on inputs.
template <bool BN>
__global__ __launch_bounds__(256) void k_agg(
    const unsigned* __restrict__ featb, unsigned* __restrict__ outb,
    const int* __restrict__ cnt, const float* __restrict__ dinv,
    const int* __restrict__ col,
    const float* __restrict__ stats, const float* __restrict__ g1g,
    const float* __restrict__ be1g, const float* __restrict__ g1s,
    const float* __restrict__ be1s, float inv_n, int n) {
  __shared__ float sc_sh[128], sf_sh[128];
  if (BN) {
    int c = threadIdx.x;
    if (c < 128) {
      float s = 0.f, q = 0.f;
#pragma unroll
      for (int k = 0; k < 8; k++) {
        s += stats[k * 256 + c];
        q += stats[k * 256 + 128 + c];
      }
      float mu = s * inv_n;
      float var = q * inv_n - mu * mu;
      float gam = (c < 64) ? g1g[c] : g1s[c - 64];
      float bet = (c < 64) ? be1g[c] : be1s[c - 64];
      float scv = gam * rsqrtf(var + 1e-5f);
      sc_sh[c] = scv;
      sf_sh[c] = bet - mu * scv;
    }
    __syncthreads();
  }
  int node = blockIdx.x * 16 + (threadIdx.x >> 4);
  if (node >= n) return;
  int t = threadIdx.x & 15;
  float sc[8], sf[8];
  if (BN) {
#pragma unroll
    for (int j = 0; j < 8; j++) {
      sc[j] = sc_sh[8 * t + j];
      sf[j] = sf_sh[8 * t + j];
    }
  }
  const uint4* f4 = (const uint4*)featb;
  float di = dinv[node];
  float acc[8];
  {
    uint4 sv = f4[node * 16 + t];
    float f[8] = {bflo(sv.x), bfhi(sv.x), bflo(sv.y), bfhi(sv.y),
                  bflo(sv.z), bfhi(sv.z), bflo(sv.w), bfhi(sv.w)};
#pragma unroll
    for (int j = 0; j < 8; j++) {
      if (BN) f[j] = fmaxf(f[j] * sc[j] + sf[j], 0.f);
      acc[j] = f[j] * di;
    }
  }
  int m = cnt[node];  // already capped at ELL_CAP
  const int4* cl = (const int4*)&col[node * ELL_CAP];
  int i = 0;
  for (; i + 8 <= m; i += 8) {
    int4 c0 = cl[i >> 2];
    int4 c1 = cl[(i >> 2) + 1];
    int ss[8] = {c0.x, c0.y, c0.z, c0.w, c1.x, c1.y, c1.z, c1.w};
    float ww[8];
    uint4 vv[8];
#pragma unroll
    for (int q = 0; q < 8; q++) {
      ww[q] = dinv[ss[q]];
      vv[q] = f4[ss[q] * 16 + t];
    }
#pragma unroll
    for (int q = 0; q < 8; q++) {
      float w = ww[q];
      uint4 v = vv[q];
      float f[8] = {bflo(v.x), bfhi(v.x), bflo(v.y), bfhi(v.y),
                    bflo(v.z), bfhi(v.z), bflo(v.w), bfhi(v.w)};
#pragma unroll
      for (int j = 0; j < 8; j++) {
        if (BN) f[j] = fmaxf(f[j] * sc[j] + sf[j], 0.f);
        acc[j] += f[j] * w;
      }
    }
  }
  for (; i + 4 <= m; i += 4) {
    int4 c4 = cl[i >> 2];
    int ss[4] = {c4.x, c4.y, c4.z, c4.w};
#pragma unroll
    for (int q = 0; q < 4; q++) {
      int s = ss[q];
      float w = dinv[s];
      uint4 v = f4[s * 16 + t];
      float f[8] = {bflo(v.x), bfhi(v.x), bflo(v.y), bfhi(v.y),
                    bflo(v.z), bfhi(v.z), bflo(v.w), bfhi(v.w)};
#pragma unroll
      for (int j = 0; j < 8; j++) {
        if (BN) f[j] = fmaxf(f[j] * sc[j] + sf[j], 0.f);
        acc[j] += f[j] * w;
      }
    }
  }
  for (; i < m; ++i) {
    int s = col[node * ELL_CAP + i];
    float w = dinv[s];
    uint4 v = f4[s * 16 + t];
    float f[8] = {bflo(v.x), bfhi(v.x), bflo(v.y), bfhi(v.y),
                  bflo(v.z), bfhi(v.z), bflo(v.w), bfhi(v.w)};
#pragma unroll
    for (int j = 0; j < 8; j++) {
      if (BN) f[j] = fmaxf(f[j] * sc[j] + sf[j], 0.f);
      acc[j] += f[j] * w;
    }
  }
  uint4 o;
  o.x = packbf(acc[0] * di, acc[1] * di);
  o.y = packbf(acc[2] * di, acc[3] * di);
  o.z = packbf(acc[4] * di, acc[5] * di);
  o.w = packbf(acc[6] * di, acc[7] * di);
  ((uint4*)outb)[node * 16 + t] = o;
}

// MFMA GEMM (swapped operands): lane owns row rowbase+(lane&15),
// cols nt*16+(lane>>4)*4+r. A bf16 row-major [M][128]. GATHER: A rows
// gathered from bf16 nodes via users/items (fo = blockIdx.y*64).
// CBF16 -> bf16 row-major C; else fp32 (+blockIdx.y slab).
template <bool CBF16, bool STATS, bool TANH, bool GATHER>
__global__ __launch_bounds__(256) void k_mgemm(
    const unsigned* __restrict__ Abf, const unsigned short* __restrict__ nodesb,
    const int* __restrict__ users, const int* __restrict__ items,
    const short* __restrict__ Wb, const float* __restrict__ bias,
    void* __restrict__ Cvp, int M, float* __restrict__ stats) {
  __shared__ short Wl[16384];   // 32 KB
  __shared__ float shs[128], shq[128];
  {
    const uint4* s4 = (const uint4*)Wb;
    uint4* d4 = (uint4*)Wl;
    for (int i = threadIdx.x; i < 2048; i += 256) d4[i] = s4[i];
  }
  if (STATS && threadIdx.x < 128) { shs[threadIdx.x] = 0.f; shq[threadIdx.x] = 0.f; }
  __syncthreads();
  int lane = threadIdx.x & 63;
  int wv = threadIdx.x >> 6;
  int l15 = lane & 15;
  int l4 = lane >> 4;
  int row = blockIdx.x * 64 + wv * 16 + l15;
  int rc = min(row, M - 1);
  bool valid = row < M;

  short8v afr[4];
  if (GATHER) {
    int fo = blockIdx.y * 64;
    const short* pu = (const short*)nodesb + users[rc] * 128 + fo;
    const short* pi = (const short*)nodesb + items[rc] * 128 + fo;
#pragma unroll
    for (int ks = 0; ks < 4; ks++) {
      int k = ks * 32 + l4 * 8;
      const short* p = (ks < 2) ? (pu + k) : (pi + (k - 64));
      afr[ks] = *(const short8v*)p;
    }
  } else {
    const short* Ab = (const short*)Abf + (size_t)rc * 128;
#pragma unroll
    for (int ks = 0; ks < 4; ks++)
      afr[ks] = *(const short8v*)(Ab + ks * 32 + l4 * 8);
  }

  f32x4 acc[8];
#pragma unroll
  for (int nt = 0; nt < 8; nt++) acc[nt] = (f32x4){0.f, 0.f, 0.f, 0.f};
#pragma unroll
  for (int nt = 0; nt < 8; nt++) {
#pragma unroll
    for (int ks = 0; ks < 4; ks++) {
      int kb = ks * 4 + l4;
      short8v w = *(const short8v*)&Wl[kb * 1024 + (nt * 16 + l15) * 8];
      acc[nt] = __builtin_amdgcn_mfma_f32_16x16x32_bf16(w, afr[ks], acc[nt], 0, 0, 0);
    }
  }

#pragma unroll
  for (int nt = 0; nt < 8; nt++) {
    int c0 = nt * 16 + l4 * 4;
    float o[4];
#pragma unroll
    for (int r = 0; r < 4; r++) o[r] = acc[nt][r];
    if (bias) {
      float4 bv = *(const float4*)(bias + c0);
      o[0] += bv.x; o[1] += bv.y; o[2] += bv.z; o[3] += bv.w;
    }
    if (TANH) {
#pragma unroll
      for (int r = 0; r < 4; r++) o[r] = tanhf(o[r]);
    }
    if (STATS) {
      float s[4], q[4];
#pragma unroll
      for (int r = 0; r < 4; r++) {
        s[r] = valid ? o[r] : 0.f;
        q[r] = s[r] * s[r];
      }
#pragma unroll
      for (int m = 1; m < 16; m <<= 1) {
#pragma unroll
        for (int r = 0; r < 4; r++) {
          s[r] += __shfl_xor(s[r], m, 64);
          q[r] += __shfl_xor(q[r], m, 64);
        }
      }
      if (l15 == 0) {
#pragma unroll
        for (int r = 0; r < 4; r++) {
          atomicAdd(&shs[c0 + r], s[r]);
          atomicAdd(&shq[c0 + r], q[r]);
        }
      }
    }
    if (valid) {
      if (CBF16) {
        unsigned* Cb = (unsigned*)Cvp;
        uint2 p;
        p.x = packbf(o[0], o[1]);
        p.y = packbf(o[2], o[3]);
        *(uint2*)&Cb[(size_t)row * 64 + (c0 >> 1)] = p;
      } else {
        float* Cf = (float*)Cvp + (size_t)blockIdx.y * M * 128;
        *(float4*)&Cf[(size_t)row * 128 + c0] = make_float4(o[0], o[1], o[2], o[3]);
      }
    }
  }
  if (STATS) {
    __syncthreads();
    if (threadIdx.x < 128) {
      float* st = stats + (blockIdx.x & 7) * 256;
      atomicAdd(&st[threadIdx.x], shs[threadIdx.x]);
      atomicAdd(&st[128 + threadIdx.x], shq[threadIdx.x]);
    }
  }
}

__global__ void k_head(const float* __restrict__ G1, const float* __restrict__ G2,
                       const unsigned short* __restrict__ nodesb,
                       const int* __restrict__ users,
                       const int* __restrict__ items, const float* __restrict__ Wsig,
                       const float* __restrict__ Wtc, const float* __restrict__ btc,
                       const float* __restrict__ Wp, const float* __restrict__ bp,
                       float* __restrict__ out, int B) {
  int l = threadIdx.x & 63;
  int wave = (blockIdx.x * 256 + threadIdx.x) >> 6;
  int nw = (gridDim.x * 256) >> 6;
  for (int b = wave; b < B; b += nw) {
    const float* g1 = G1 + (size_t)b * 128;
    const float* g2 = G2 + (size_t)b * 128;
    int u = users[b], it = items[b];
    float h1a = g1[l], h1b = g1[64 + l];
    float h2a = g2[l], h2b = g2[64 + l];
    float ga = __uint_as_float((unsigned)nodesb[u * 128 + l] << 16);
    float gb = __uint_as_float((unsigned)nodesb[it * 128 + l] << 16);
    float zp = h1a * Wsig[l] + h1b * Wsig[64 + l] + h2a * Wsig[128 + l] + h2b * Wsig[192 + l];
    float z = wred64(zp);
    z = 1.f / (1.f + expf(-z));
    float fa = z * h1a + (1.f - z) * h2a;
    float fb = z * h1b + (1.f - z) * h2b;
    float p0 = wred64(fa * Wp[l * 2] + fb * Wp[(64 + l) * 2]);
    float p1 = wred64(fa * Wp[l * 2 + 1] + fb * Wp[(64 + l) * 2 + 1]);
    float t0 = wred64(ga * Wtc[l * 4] + gb * Wtc[(64 + l) * 4]);
    float t1 = wred64(ga * Wtc[l * 4 + 1] + gb * Wtc[(64 + l) * 4 + 1]);
    float t2 = wred64(ga * Wtc[l * 4 + 2] + gb * Wtc[(64 + l) * 4 + 2]);
    float t3 = wred64(ga * Wtc[l * 4 + 3] + gb * Wtc[(64 + l) * 4 + 3]);
    if (l == 0) {
      out[b * 2] = p0 + bp[0];
      out[b * 2 + 1] = p1 + bp[1];
      float* go = out + 2 * B;
      go[b * 4] = t0 + btc[0];
      go[b * 4 + 1] = t1 + btc[1];
      go[b * 4 + 2] = t2 + btc[2];
      go[b * 4 + 3] = t3 + btc[3];
    }
  }
}

extern "C" void kernel_launch(void* const* d_in, const int* in_sizes, int n_in,
                              void* d_out, int out_size, void* d_ws, size_t ws_size,
                              hipStream_t stream) {
  const float* x = (const float*)d_in[0];
  const int* ei = (const int*)d_in[1];
  const int* users = (const int*)d_in[2];
  const int* items = (const int*)d_in[3];
  const float* W1g = (const float*)d_in[4];
  const float* b1g = (const float*)d_in[5];
  const float* g1g = (const float*)d_in[6];
  const float* be1g = (const float*)d_in[7];
  const float* W2g = (const float*)d_in[8];
  const float* b2g = (const float*)d_in[9];
  const float* W1s = (const float*)d_in[10];
  const float* b1s = (const float*)d_in[11];
  const float* g1s = (const float*)d_in[12];
  const float* be1s = (const float*)d_in[13];
  const float* W2s = (const float*)d_in[14];
  const float* b2s = (const float*)d_in[15];
  const float* Wf1 = (const float*)d_in[16];
  const float* Wsig = (const float*)d_in[17];
  const float* Wtc = (const float*)d_in[18];
  const float* btc = (const float*)d_in[19];
  const float* Wp = (const float*)d_in[20];
  const float* bp = (const float*)d_in[21];

  int n = in_sizes[0] / 128;   // 100000
  int E = in_sizes[1] / 2;     // 1600000
  int B = in_sizes[2];         // 16384
  int NB = (n + 255) >> 8;     // 391
  const int* srcp = ei;
  const int* dstp = ei + E;
  float* out = (float*)d_out;

  char* w = (char*)d_ws;
  auto alloc = [&](size_t bytes) -> char* {
    char* p = w;
    w += (bytes + 255) & ~(size_t)255;
    return p;
  };
  unsigned* xab = (unsigned*)alloc((size_t)n * 64 * 4);     // bf16 agg out
  float* big1 = (float*)alloc((size_t)n * 128 * 4);         // hb bf16 -> nodesb bf16
  unsigned* bff = (unsigned*)alloc((size_t)n * 128 * 2);    // x bf16; later G1/G2
  int* col = (int*)alloc((size_t)n * ELL_CAP * 4);          // ELL
  unsigned* ebuf = (unsigned*)alloc((size_t)NB * BCAP * 4); // bucketed edges
  int* cnt = (int*)alloc((size_t)n * 4);
  float* dinv = (float*)alloc((size_t)n * 4);
  int* gbump = (int*)alloc(512 * 4);
  short* Wb1 = (short*)alloc(16384 * 2);
  short* Wb2 = (short*)alloc(16384 * 2);
  short* WbH = (short*)alloc(16384 * 2);
  float* bc1 = (float*)alloc(512);
  float* bc2 = (float*)alloc(512);
  float* stats = (float*)alloc(2048 * 4);

  k_prep<<<(n * 16 + 255) / 256, 256, 0, stream>>>(
      x, bff, gbump, stats, W1g, b1g, W1s, b1s, W2g, b2g, W2s, b2s, Wf1,
      Wb1, Wb2, WbH, bc1, bc2, n, NB);
  k_bucketA<<<(E + ACHUNK - 1) / ACHUNK, 256, 0, stream>>>(srcp, dstp, gbump, ebuf, E, NB);
  k_csrB<<<NB, 256, 0, stream>>>(ebuf, gbump, cnt, dinv, col, n);

  unsigned* hb = (unsigned*)big1;
  unsigned short* nodesb = (unsigned short*)big1;

  // layer 1: xa = S@x (bf16); h = xa @ [W1g|W1s] + bc1 (bf16 out, BN stats)
  k_agg<false><<<(n + 15) / 16, 256, 0, stream>>>(bff, xab, cnt, dinv, col,
                                                  nullptr, nullptr, nullptr,
                                                  nullptr, nullptr, 0.f, n);
  k_mgemm<true, true, false, false><<<(n + 63) / 64, 256, 0, stream>>>(
      xab, nullptr, nullptr, nullptr, Wb1, bc1, hb, n, stats);

  // layer 2: ha = S@relu(bn(h)); nodes = ha @ blockdiag(W2g,W2s) + bc2 (bf16)
  k_agg<true><<<(n + 15) / 16, 256, 0, stream>>>(hb, xab, cnt, dinv, col,
                                                 stats, g1g, be1g, g1s, be1s,
                                                 1.f / (float)n, n);
  k_mgemm<true, false, false, false><<<(n + 63) / 64, 256, 0, stream>>>(
      xab, nullptr, nullptr, nullptr, Wb2, bc2, nodesb, n, nullptr);

  // head: gathered tanh-GEMMs from bf16 nodes (y=0 gen->G1, y=1 spec->G2)
  float* G1 = (float*)bff;
  dim3 gh((B + 63) / 64, 2);
  k_mgemm<false, false, true, true><<<gh, 256, 0, stream>>>(
      nullptr, nodesb, users, items, WbH, nullptr, G1, B, nullptr);
  float* G2 = G1 + (size_t)B * 128;
  k_head<<<2048, 256, 0, stream>>>(G1, G2, nodesb, users, items, Wsig, Wtc, btc,
                                   Wp, bp, out, B);
}

// Round 10
// 250.464 us; speedup vs baseline: 2.0058x; 1.1012x over previous
//
#include <hip/hip_runtime.h>
#include <hip/hip_bf16.h>

// ---------------------------------------------------------------------------
// AMMN_Net: dual 2-layer GCN + gated fusion head.
// R10 = best-verified pieces only:
//  - k_agg: 16 lanes/node, 4-deep unroll (44-48 VGPR, max occupancy -- agg is
//    latency-bound: dur*occ==const across R6/R7/R9), dinv table from csrB.
//    NO degree sort (R7 net-neg), NO slicing (R8 fail), NO 8-deep (R9 fail).
//  - bucketed two-phase ELL build (R5), MFMA GEMMs w/ swapped operands (R6),
//    BN stats fused in GEMM1, BN+ReLU fused in agg2, bf16 nodes (R9).
//  - NEW: k_fhead fuses both head tanh-GEMMs + gate/link/tc epilogue into one
//    kernel (in-register, shfl row-reductions) -- kills k_head and the 33MB
//    G1/G2 round trip. 8 kernel launches.
// ---------------------------------------------------------------------------

#define ELL_CAP 64
#define BCAP 8192
#define ACHUNK 5120

typedef __attribute__((ext_vector_type(8))) short short8v;   // 8 bf16
typedef __attribute__((ext_vector_type(4))) float f32x4;

static __device__ __forceinline__ unsigned short f2bf(float f) {
  unsigned u = __float_as_uint(f);
  unsigned r = (u + 0x7fffu + ((u >> 16) & 1u)) >> 16;  // RNE
  return (unsigned short)r;
}
static __device__ __forceinline__ unsigned packbf(float a, float b) {
  return (unsigned)f2bf(a) | ((unsigned)f2bf(b) << 16);
}
static __device__ __forceinline__ float bflo(unsigned u) {
  return __uint_as_float(u << 16);
}
static __device__ __forceinline__ float bfhi(unsigned u) {
  return __uint_as_float(u & 0xffff0000u);
}
static __device__ __forceinline__ float bf2f(short s) {
  return __uint_as_float((unsigned)(unsigned short)s << 16);
}

// prep: x->bf16 row-major; pack Wb1/Wb2(block-diag)/WbH bf16 [k/8][128][8];
// biases; init gbump + stats.
__global__ void k_prep(const float* __restrict__ x, unsigned* __restrict__ bff,
                       int* __restrict__ gbump, float* __restrict__ stats,
                       const float* __restrict__ W1g, const float* __restrict__ b1g,
                       const float* __restrict__ W1s, const float* __restrict__ b1s,
                       const float* __restrict__ W2g, const float* __restrict__ b2g,
                       const float* __restrict__ W2s, const float* __restrict__ b2s,
                       const float* __restrict__ Wf1,
                       short* __restrict__ Wb1, short* __restrict__ Wb2,
                       short* __restrict__ WbH, float* __restrict__ bc1,
                       float* __restrict__ bc2, int n, int NB) {
  int idx = blockIdx.x * 256 + threadIdx.x;
  int n16 = n * 16;
  if (idx < n16) {
    const float4* f4 = (const float4*)x;
    float4 a = f4[idx * 2], b = f4[idx * 2 + 1];
    uint4 o;
    o.x = packbf(a.x, a.y);
    o.y = packbf(a.z, a.w);
    o.z = packbf(b.x, b.y);
    o.w = packbf(b.z, b.w);
    ((uint4*)bff)[idx] = o;
  }
  if (idx < 16384) {
    int k = idx >> 7, c = idx & 127;
    int pi = (k >> 3) * 1024 + c * 8 + (k & 7);  // [k/8][c][k&7]
    float w1 = (c < 64) ? W1g[k * 64 + c] : W1s[k * 64 + (c - 64)];
    Wb1[pi] = (short)f2bf(w1);
    float w2 = 0.f;
    if (k < 64 && c < 64) w2 = W2g[k * 64 + c];
    else if (k >= 64 && c >= 64) w2 = W2s[(k - 64) * 64 + (c - 64)];
    Wb2[pi] = (short)f2bf(w2);
    WbH[pi] = (short)f2bf(Wf1[k * 128 + c]);
  }
  if (idx < 128) {
    bc1[idx] = (idx < 64) ? b1g[idx] : b1s[idx - 64];
    bc2[idx] = (idx < 64) ? b2g[idx] : b2s[idx - 64];
  }
  if (idx < NB) gbump[idx] = idx * BCAP;
  if (idx < 2048) stats[idx] = 0.f;
}

// Pass A: bucket edges by dst>>8 (one global atomic per block-bucket)
__global__ __launch_bounds__(256) void k_bucketA(
    const int* __restrict__ src, const int* __restrict__ dst,
    int* __restrict__ gbump, unsigned* __restrict__ ebuf, int E, int NB) {
  __shared__ int hist[512];
  __shared__ int gbase[512];
  int t = threadIdx.x;
  int e0 = blockIdx.x * ACHUNK;
  int m = min(ACHUNK, E - e0);
  for (int b = t; b < NB; b += 256) hist[b] = 0;
  __syncthreads();
  for (int i = t; i < m; i += 256) atomicAdd(&hist[dst[e0 + i] >> 8], 1);
  __syncthreads();
  for (int b = t; b < NB; b += 256) {
    gbase[b] = hist[b] ? atomicAdd(&gbump[b], hist[b]) : 0;
    hist[b] = 0;
  }
  __syncthreads();
  for (int i = t; i < m; i += 256) {
    int d = dst[e0 + i];
    int s = src[e0 + i];
    int b = d >> 8;
    int off = gbase[b] + atomicAdd(&hist[b], 1);
    if (off < (b + 1) * BCAP)
      ebuf[off] = ((unsigned)s << 8) | (unsigned)(d & 255);
  }
}

// Pass B: block-per-bucket; LDS bump -> ELL col + capped cnt + dinv
__global__ __launch_bounds__(256) void k_csrB(
    const unsigned* __restrict__ ebuf, const int* __restrict__ gbump,
    int* __restrict__ cnt, float* __restrict__ dinv, int* __restrict__ col,
    int n) {
  __shared__ int lbump[256];
  int b = blockIdx.x;
  lbump[threadIdx.x] = 0;
  __syncthreads();
  int base = b * BCAP;
  int m = min(gbump[b] - base, BCAP);
  for (int i = threadIdx.x; i < m; i += 256) {
    unsigned p = ebuf[base + i];
    int dloc = p & 255;
    int slot = atomicAdd(&lbump[dloc], 1);
    if (slot < ELL_CAP)
      col[(b * 256 + dloc) * ELL_CAP + slot] = (int)(p >> 8);
  }
  __syncthreads();
  int node = b * 256 + threadIdx.x;
  if (node < n) {
    int c = lbump[threadIdx.x];
    cnt[node] = min(c, ELL_CAP);
    dinv[node] = rsqrtf((float)(c + 1));  // true degree for norm
  }
}

// aggregation: 16 lanes/node (uint4 = 16B of the 256B bf16 row), 4-deep
// unroll, dinv table. Optional fused BN+ReLU on inputs.
template <bool BN>
__global__ __launch_bounds__(256) void k_agg(
    const unsigned* __restrict__ featb, unsigned* __restrict__ outb,
    const int* __restrict__ cnt, const float* __restrict__ dinv,
    const int* __restrict__ col,
    const float* __restrict__ stats, const float* __restrict__ g1g,
    const float* __restrict__ be1g, const float* __restrict__ g1s,
    const float* __restrict__ be1s, float inv_n, int n) {
  __shared__ float sc_sh[128], sf_sh[128];
  if (BN) {
    int c = threadIdx.x;
    if (c < 128) {
      float s = 0.f, q = 0.f;
#pragma unroll
      for (int k = 0; k < 8; k++) {
        s += stats[k * 256 + c];
        q += stats[k * 256 + 128 + c];
      }
      float mu = s * inv_n;
      float var = q * inv_n - mu * mu;
      float gam = (c < 64) ? g1g[c] : g1s[c - 64];
      float bet = (c < 64) ? be1g[c] : be1s[c - 64];
      float scv = gam * rsqrtf(var + 1e-5f);
      sc_sh[c] = scv;
      sf_sh[c] = bet - mu * scv;
    }
    __syncthreads();
  }
  int node = blockIdx.x * 16 + (threadIdx.x >> 4);
  if (node >= n) return;
  int t = threadIdx.x & 15;
  float sc[8], sf[8];
  if (BN) {
#pragma unroll
    for (int j = 0; j < 8; j++) {
      sc[j] = sc_sh[8 * t + j];
      sf[j] = sf_sh[8 * t + j];
    }
  }
  const uint4* f4 = (const uint4*)featb;
  float di = dinv[node];
  float acc[8];
  {
    uint4 sv = f4[node * 16 + t];
    float f[8] = {bflo(sv.x), bfhi(sv.x), bflo(sv.y), bfhi(sv.y),
                  bflo(sv.z), bfhi(sv.z), bflo(sv.w), bfhi(sv.w)};
#pragma unroll
    for (int j = 0; j < 8; j++) {
      if (BN) f[j] = fmaxf(f[j] * sc[j] + sf[j], 0.f);
      acc[j] = f[j] * di;
    }
  }
  int m = cnt[node];  // capped at ELL_CAP
  const int4* cl = (const int4*)&col[node * ELL_CAP];
  int i = 0;
  for (; i + 4 <= m; i += 4) {
    int4 c4 = cl[i >> 2];
    int ss[4] = {c4.x, c4.y, c4.z, c4.w};
#pragma unroll
    for (int q = 0; q < 4; q++) {
      int s = ss[q];
      float w = dinv[s];
      uint4 v = f4[s * 16 + t];
      float f[8] = {bflo(v.x), bfhi(v.x), bflo(v.y), bfhi(v.y),
                    bflo(v.z), bfhi(v.z), bflo(v.w), bfhi(v.w)};
#pragma unroll
      for (int j = 0; j < 8; j++) {
        if (BN) f[j] = fmaxf(f[j] * sc[j] + sf[j], 0.f);
        acc[j] += f[j] * w;
      }
    }
  }
  for (; i < m; ++i) {
    int s = col[node * ELL_CAP + i];
    float w = dinv[s];
    uint4 v = f4[s * 16 + t];
    float f[8] = {bflo(v.x), bfhi(v.x), bflo(v.y), bfhi(v.y),
                  bflo(v.z), bfhi(v.z), bflo(v.w), bfhi(v.w)};
#pragma unroll
    for (int j = 0; j < 8; j++) {
      if (BN) f[j] = fmaxf(f[j] * sc[j] + sf[j], 0.f);
      acc[j] += f[j] * w;
    }
  }
  uint4 o;
  o.x = packbf(acc[0] * di, acc[1] * di);
  o.y = packbf(acc[2] * di, acc[3] * di);
  o.z = packbf(acc[4] * di, acc[5] * di);
  o.w = packbf(acc[6] * di, acc[7] * di);
  ((uint4*)outb)[node * 16 + t] = o;
}

// MFMA GEMM (swapped operands): lane owns row rowbase+(lane&15),
// cols nt*16+(lane>>4)*4+r. A bf16 row-major [M][128].
// CBF16 -> bf16 row-major C; else fp32.
template <bool CBF16, bool STATS>
__global__ __launch_bounds__(256) void k_mgemm(
    const unsigned* __restrict__ Abf,
    const short* __restrict__ Wb, const float* __restrict__ bias,
    void* __restrict__ Cvp, int M, float* __restrict__ stats) {
  __shared__ short Wl[16384];   // 32 KB
  __shared__ float shs[128], shq[128];
  {
    const uint4* s4 = (const uint4*)Wb;
    uint4* d4 = (uint4*)Wl;
    for (int i = threadIdx.x; i < 2048; i += 256) d4[i] = s4[i];
  }
  if (STATS && threadIdx.x < 128) { shs[threadIdx.x] = 0.f; shq[threadIdx.x] = 0.f; }
  __syncthreads();
  int lane = threadIdx.x & 63;
  int wv = threadIdx.x >> 6;
  int l15 = lane & 15;
  int l4 = lane >> 4;
  int row = blockIdx.x * 64 + wv * 16 + l15;
  int rc = min(row, M - 1);
  bool valid = row < M;

  short8v afr[4];
  const short* Ab = (const short*)Abf + (size_t)rc * 128;
#pragma unroll
  for (int ks = 0; ks < 4; ks++)
    afr[ks] = *(const short8v*)(Ab + ks * 32 + l4 * 8);

  f32x4 acc[8];
#pragma unroll
  for (int nt = 0; nt < 8; nt++) acc[nt] = (f32x4){0.f, 0.f, 0.f, 0.f};
#pragma unroll
  for (int nt = 0; nt < 8; nt++) {
#pragma unroll
    for (int ks = 0; ks < 4; ks++) {
      int kb = ks * 4 + l4;
      short8v w = *(const short8v*)&Wl[kb * 1024 + (nt * 16 + l15) * 8];
      acc[nt] = __builtin_amdgcn_mfma_f32_16x16x32_bf16(w, afr[ks], acc[nt], 0, 0, 0);
    }
  }

#pragma unroll
  for (int nt = 0; nt < 8; nt++) {
    int c0 = nt * 16 + l4 * 4;
    float o[4];
#pragma unroll
    for (int r = 0; r < 4; r++) o[r] = acc[nt][r];
    if (bias) {
      float4 bv = *(const float4*)(bias + c0);
      o[0] += bv.x; o[1] += bv.y; o[2] += bv.z; o[3] += bv.w;
    }
    if (STATS) {
      float s[4], q[4];
#pragma unroll
      for (int r = 0; r < 4; r++) {
        s[r] = valid ? o[r] : 0.f;
        q[r] = s[r] * s[r];
      }
#pragma unroll
      for (int m = 1; m < 16; m <<= 1) {
#pragma unroll
        for (int r = 0; r < 4; r++) {
          s[r] += __shfl_xor(s[r], m, 64);
          q[r] += __shfl_xor(q[r], m, 64);
        }
      }
      if (l15 == 0) {
#pragma unroll
        for (int r = 0; r < 4; r++) {
          atomicAdd(&shs[c0 + r], s[r]);
          atomicAdd(&shq[c0 + r], q[r]);
        }
      }
    }
    if (valid) {
      if (CBF16) {
        unsigned* Cb = (unsigned*)Cvp;
        uint2 p;
        p.x = packbf(o[0], o[1]);
        p.y = packbf(o[2], o[3]);
        *(uint2*)&Cb[(size_t)row * 64 + (c0 >> 1)] = p;
      } else {
        float* Cf = (float*)Cvp;
        *(float4*)&Cf[(size_t)row * 128 + c0] = make_float4(o[0], o[1], o[2], o[3]);
      }
    }
  }
  if (STATS) {
    __syncthreads();
    if (threadIdx.x < 128) {
      float* st = stats + (blockIdx.x & 7) * 256;
      atomicAdd(&st[threadIdx.x], shs[threadIdx.x]);
      atomicAdd(&st[128 + threadIdx.x], shq[threadIdx.x]);
    }
  }
}

// Fused head: per 64 batch rows, compute h1=tanh(gen@Wf1), h2=tanh(spec@Wf1)
// via MFMA (gen/spec fragments gathered from bf16 nodes), then the full gate/
// link/tc epilogue in-register. Row's 4 lanes (l15, l4=0..3) hold 32 cols
// each; row reductions via shfl_xor(16),(32).
__global__ __launch_bounds__(256) void k_fhead(
    const unsigned short* __restrict__ nodesb,
    const int* __restrict__ users, const int* __restrict__ items,
    const short* __restrict__ WbH, const float* __restrict__ Wsig,
    const float* __restrict__ Wtc, const float* __restrict__ btc,
    const float* __restrict__ Wp, const float* __restrict__ bp,
    float* __restrict__ out, int B) {
  __shared__ short Wl[16384];           // Wf1 packed, 32 KB
  __shared__ float WsigL[256], WpL[256], WtcL[512];
  {
    const uint4* s4 = (const uint4*)WbH;
    uint4* d4 = (uint4*)Wl;
    for (int i = threadIdx.x; i < 2048; i += 256) d4[i] = s4[i];
    if (threadIdx.x < 256) {
      WsigL[threadIdx.x] = Wsig[threadIdx.x];
      WpL[threadIdx.x] = Wp[threadIdx.x];
    }
    for (int i = threadIdx.x; i < 512; i += 256) WtcL[i] = Wtc[i];
  }
  __syncthreads();
  int lane = threadIdx.x & 63;
  int wv = threadIdx.x >> 6;
  int l15 = lane & 15;
  int l4 = lane >> 4;
  int row = blockIdx.x * 64 + wv * 16 + l15;
  int rc = min(row, B - 1);
  int u = users[rc], it = items[rc];
  const short* pu = (const short*)nodesb + u * 128;
  const short* pi = (const short*)nodesb + it * 128;

  short8v ag[4], as[4];
#pragma unroll
  for (int ks = 0; ks < 4; ks++) {
    int k = ks * 32 + l4 * 8;
    const short* pg = (ks < 2) ? (pu + k) : (pi + (k - 64));
    const short* ps = (ks < 2) ? (pu + 64 + k) : (pi + k);
    ag[ks] = *(const short8v*)pg;
    as[ks] = *(const short8v*)ps;
  }

  f32x4 a1[8], a2[8];
#pragma unroll
  for (int nt = 0; nt < 8; nt++) {
    a1[nt] = (f32x4){0.f, 0.f, 0.f, 0.f};
    a2[nt] = (f32x4){0.f, 0.f, 0.f, 0.f};
  }
#pragma unroll
  for (int nt = 0; nt < 8; nt++) {
#pragma unroll
    for (int ks = 0; ks < 4; ks++) {
      int kb = ks * 4 + l4;
      short8v w = *(const short8v*)&Wl[kb * 1024 + (nt * 16 + l15) * 8];
      a1[nt] = __builtin_amdgcn_mfma_f32_16x16x32_bf16(w, ag[ks], a1[nt], 0, 0, 0);
      a2[nt] = __builtin_amdgcn_mfma_f32_16x16x32_bf16(w, as[ks], a2[nt], 0, 0, 0);
    }
  }

  // tanh + z partial
  float zp = 0.f;
#pragma unroll
  for (int nt = 0; nt < 8; nt++) {
    int c0 = nt * 16 + l4 * 4;
#pragma unroll
    for (int r = 0; r < 4; r++) {
      float h1 = tanhf(a1[nt][r]);
      float h2 = tanhf(a2[nt][r]);
      a1[nt][r] = h1;
      a2[nt][r] = h2;
      zp += h1 * WsigL[c0 + r] + h2 * WsigL[128 + c0 + r];
    }
  }
  zp += __shfl_xor(zp, 16, 64);
  zp += __shfl_xor(zp, 32, 64);
  float z = 1.f / (1.f + expf(-zp));

  // link partials
  float p0 = 0.f, p1 = 0.f;
#pragma unroll
  for (int nt = 0; nt < 8; nt++) {
    int c0 = nt * 16 + l4 * 4;
#pragma unroll
    for (int r = 0; r < 4; r++) {
      float fu = z * a1[nt][r] + (1.f - z) * a2[nt][r];
      p0 += fu * WpL[(c0 + r) * 2];
      p1 += fu * WpL[(c0 + r) * 2 + 1];
    }
  }
  // tc partials from raw gen fragments
  float t0 = 0.f, t1 = 0.f, t2 = 0.f, t3 = 0.f;
#pragma unroll
  for (int ks = 0; ks < 4; ks++) {
    int kbase = ks * 32 + l4 * 8;
#pragma unroll
    for (int j = 0; j < 8; j++) {
      float g = bf2f(ag[ks][j]);
      int c = kbase + j;
      t0 += g * WtcL[c * 4];
      t1 += g * WtcL[c * 4 + 1];
      t2 += g * WtcL[c * 4 + 2];
      t3 += g * WtcL[c * 4 + 3];
    }
  }
  p0 += __shfl_xor(p0, 16, 64); p0 += __shfl_xor(p0, 32, 64);
  p1 += __shfl_xor(p1, 16, 64); p1 += __shfl_xor(p1, 32, 64);
  t0 += __shfl_xor(t0, 16, 64); t0 += __shfl_xor(t0, 32, 64);
  t1 += __shfl_xor(t1, 16, 64); t1 += __shfl_xor(t1, 32, 64);
  t2 += __shfl_xor(t2, 16, 64); t2 += __shfl_xor(t2, 32, 64);
  t3 += __shfl_xor(t3, 16, 64); t3 += __shfl_xor(t3, 32, 64);

  if (l4 == 0 && row < B) {
    out[row * 2] = p0 + bp[0];
    out[row * 2 + 1] = p1 + bp[1];
    float* go = out + 2 * B;
    go[row * 4] = t0 + btc[0];
    go[row * 4 + 1] = t1 + btc[1];
    go[row * 4 + 2] = t2 + btc[2];
    go[row * 4 + 3] = t3 + btc[3];
  }
}

extern "C" void kernel_launch(void* const* d_in, const int* in_sizes, int n_in,
                              void* d_out, int out_size, void* d_ws, size_t ws_size,
                              hipStream_t stream) {
  const float* x = (const float*)d_in[0];
  const int* ei = (const int*)d_in[1];
  const int* users = (const int*)d_in[2];
  const int* items = (const int*)d_in[3];
  const float* W1g = (const float*)d_in[4];
  const float* b1g = (const float*)d_in[5];
  const float* g1g = (const float*)d_in[6];
  const float* be1g = (const float*)d_in[7];
  const float* W2g = (const float*)d_in[8];
  const float* b2g = (const float*)d_in[9];
  const float* W1s = (const float*)d_in[10];
  const float* b1s = (const float*)d_in[11];
  const float* g1s = (const float*)d_in[12];
  const float* be1s = (const float*)d_in[13];
  const float* W2s = (const float*)d_in[14];
  const float* b2s = (const float*)d_in[15];
  const float* Wf1 = (const float*)d_in[16];
  const float* Wsig = (const float*)d_in[17];
  const float* Wtc = (const float*)d_in[18];
  const float* btc = (const float*)d_in[19];
  const float* Wp = (const float*)d_in[20];
  const float* bp = (const float*)d_in[21];

  int n = in_sizes[0] / 128;   // 100000
  int E = in_sizes[1] / 2;     // 1600000
  int B = in_sizes[2];         // 16384
  int NB = (n + 255) >> 8;     // 391
  const int* srcp = ei;
  const int* dstp = ei + E;
  float* out = (float*)d_out;

  char* w = (char*)d_ws;
  auto alloc = [&](size_t bytes) -> char* {
    char* p = w;
    w += (bytes + 255) & ~(size_t)255;
    return p;
  };
  unsigned* xab = (unsigned*)alloc((size_t)n * 64 * 4);     // bf16 agg out
  float* big1 = (float*)alloc((size_t)n * 128 * 4);         // hb bf16 / nodesb bf16
  unsigned* bff = (unsigned*)alloc((size_t)n * 128 * 2);    // x bf16
  int* col = (int*)alloc((size_t)n * ELL_CAP * 4);          // ELL
  unsigned* ebuf = (unsigned*)alloc((size_t)NB * BCAP * 4); // bucketed edges
  int* cnt = (int*)alloc((size_t)n * 4);
  float* dinv = (float*)alloc((size_t)n * 4);
  int* gbump = (int*)alloc(512 * 4);
  short* Wb1 = (short*)alloc(16384 * 2);
  short* Wb2 = (short*)alloc(16384 * 2);
  short* WbH = (short*)alloc(16384 * 2);
  float* bc1 = (float*)alloc(512);
  float* bc2 = (float*)alloc(512);
  float* stats = (float*)alloc(2048 * 4);

  k_prep<<<(n * 16 + 255) / 256, 256, 0, stream>>>(
      x, bff, gbump, stats, W1g, b1g, W1s, b1s, W2g, b2g, W2s, b2s, Wf1,
      Wb1, Wb2, WbH, bc1, bc2, n, NB);
  k_bucketA<<<(E + ACHUNK - 1) / ACHUNK, 256, 0, stream>>>(srcp, dstp, gbump, ebuf, E, NB);
  k_csrB<<<NB, 256, 0, stream>>>(ebuf, gbump, cnt, dinv, col, n);

  unsigned* hb = (unsigned*)big1;
  unsigned short* nodesb = (unsigned short*)big1;

  // layer 1: xa = S@x (bf16); h = xa @ [W1g|W1s] + bc1 (bf16 out, BN stats)
  k_agg<false><<<(n + 15) / 16, 256, 0, stream>>>(bff, xab, cnt, dinv, col,
                                                  nullptr, nullptr, nullptr,
                                                  nullptr, nullptr, 0.f, n);
  k_mgemm<true, true><<<(n + 63) / 64, 256, 0, stream>>>(xab, Wb1, bc1, hb, n, stats);

  // layer 2: ha = S@relu(bn(h)); nodes = ha @ blockdiag(W2g,W2s) + bc2 (bf16)
  k_agg<true><<<(n + 15) / 16, 256, 0, stream>>>(hb, xab, cnt, dinv, col,
                                                 stats, g1g, be1g, g1s, be1s,
                                                 1.f / (float)n, n);
  k_mgemm<true, false><<<(n + 63) / 64, 256, 0, stream>>>(xab, Wb2, bc2, nodesb, n, nullptr);

  // fused head: both tanh-GEMMs + gate/link/tc epilogue in one kernel
  k_fhead<<<(B + 63) / 64, 256, 0, stream>>>(nodesb, users, items, WbH, Wsig,
                                             Wtc, btc, Wp, bp, out, B);
}